// Round 12
// baseline (509.652 us; speedup 1.0000x reference)
//
#include <hip/hip_runtime.h>
#include <hip/hip_bf16.h>
#include <hip/hip_fp16.h>
#include <math.h>

#define BB 32
#define TT 8
#define PP 196
#define DD 768
#define MM 10
#define NCLS 100
#define NIDX 98

typedef __attribute__((ext_vector_type(8))) short short8v;
typedef __attribute__((ext_vector_type(4))) float float4v;

__device__ __forceinline__ float fast_tanh(float x) {
    float e = __expf(2.0f * x);
    return 1.0f - 2.0f / (e + 1.0f);
}
__device__ __forceinline__ unsigned short f2bf(float x) {
    __hip_bfloat16 h = __float2bfloat16(x);
    return *(unsigned short*)&h;
}
__device__ __forceinline__ float bf2f(unsigned short h) {
    return __uint_as_float(((unsigned)h) << 16);
}
__device__ __forceinline__ unsigned short f2h(float x) {
    __half h = __float2half(x);
    return *(unsigned short*)&h;
}
__device__ __forceinline__ float h2f(unsigned short u) {
    __half h = *(__half*)&u;
    return __half2float(h);
}

// ---------------------------------------------------------------------------
// K-1 fused prep: blocks [0,1024) vis f32->bf16 (+mask detect in block 0);
// blocks [1024,1600) Wav transpose+rtne; blocks [1600,1696) feats partials.
// ---------------------------------------------------------------------------
__global__ __launch_bounds__(768) void k_prep_all(
    const float* __restrict__ vis, unsigned short* __restrict__ visb,
    const unsigned int* __restrict__ rm, int* __restrict__ mode,
    const float* __restrict__ Wav, unsigned short* __restrict__ Wht,
    const float* __restrict__ causal, const float* __restrict__ Wf,
    const float* __restrict__ Wf2,
    float* __restrict__ pf, float* __restrict__ pf2) {
    int t = threadIdx.x;
    int bid = blockIdx.x;
    if (bid < 1024) {
        const size_t NC = (size_t)BB * TT * PP * DD / 8;   // uint4 chunks
        size_t gid = (size_t)bid * 768 + t;
        for (size_t i = gid; i < NC; i += 1024 * 768) {
            const float4* s = (const float4*)(vis + i * 8);
            float4 x = s[0], y = s[1];
            __hip_bfloat162 h;
            unsigned int u0, u1, u2, u3;
            h = __float22bfloat162_rn(make_float2(x.x, x.y)); u0 = *(unsigned int*)&h;
            h = __float22bfloat162_rn(make_float2(x.z, x.w)); u1 = *(unsigned int*)&h;
            h = __float22bfloat162_rn(make_float2(y.x, y.y)); u2 = *(unsigned int*)&h;
            h = __float22bfloat162_rn(make_float2(y.z, y.w)); u3 = *(unsigned int*)&h;
            uint4 o; o.x = u0; o.y = u1; o.z = u2; o.w = u3;
            ((uint4*)visb)[i] = o;
        }
        if (bid == 0) {
            __shared__ int f_ni, f_nf;
            if (t == 0) { f_ni = 0; f_nf = 0; }
            __syncthreads();
            int ni = 0, nf = 0;
            for (int i = t; i < 16384; i += 768) {
                unsigned int v = rm[i];
                ni |= (v > 1u) ? 1 : 0;
                nf |= (v != 0u && v != 0x3F800000u) ? 1 : 0;
            }
            if (ni) atomicOr(&f_ni, 1);
            if (nf) atomicOr(&f_nf, 1);
            __syncthreads();
            if (t == 0) *mode = f_ni ? (f_nf ? 2 : 1) : 0;
        }
    } else if (bid < 1600) {
        __shared__ float tile[32][33];
        int bb = bid - 1024;
        int bn = (bb % 24) * 32;
        int bk = (bb / 24) * 32;
        if (t < 256) {
            int tx = t & 31, ty = t >> 5;
            #pragma unroll
            for (int i = 0; i < 4; ++i)
                tile[ty + i * 8][tx] = Wav[(size_t)(bk + ty + i * 8) * DD + bn + tx];
        }
        __syncthreads();
        if (t < 256) {
            int tx = t & 31, ty = t >> 5;
            #pragma unroll
            for (int i = 0; i < 4; ++i) {
                int n = bn + ty + i * 8, k = bk + tx;
                Wht[(size_t)n * DD + k] = f2bf(tile[tx][ty + i * 8]);
            }
        }
    } else {
        __shared__ float cs[MM][256];
        __shared__ float red[MM][12];
        int bb = bid - 1600;
        int b = bb % 32, kc = bb / 32;
        int k0 = kc * 256;
        for (int i = t; i < MM * 256; i += 768)
            cs[i >> 8][i & 255] = causal[((size_t)b * MM + (i >> 8)) * DD + k0 + (i & 255)];
        __syncthreads();
        int wave = t >> 6, lane = t & 63;
        float w2v = (t < 256) ? Wf2[k0 + t] : 0.f;
        #pragma unroll
        for (int m = 0; m < MM; ++m) {
            float p = (t < 256) ? cs[m][t] * w2v : 0.f;
            #pragma unroll
            for (int o = 32; o > 0; o >>= 1) p += __shfl_down(p, o);
            if (lane == 0) red[m][wave] = p;
        }
        __syncthreads();
        if (t < MM) {
            float s = 0.f;
            #pragma unroll
            for (int wv = 0; wv < 4; ++wv) s += red[t][wv];
            pf2[(b * 3 + kc) * MM + t] = s;
        }
        float acc[MM];
        #pragma unroll
        for (int m = 0; m < MM; ++m) acc[m] = 0.f;
        #pragma unroll 4
        for (int k = 0; k < 256; ++k) {
            float wv = Wf[(size_t)(k0 + k) * DD + t];
            #pragma unroll
            for (int m = 0; m < MM; ++m) acc[m] = fmaf(cs[m][k], wv, acc[m]);
        }
        #pragma unroll
        for (int m = 0; m < MM; ++m)
            pf[(((size_t)b * 3 + kc) * MM + m) * DD + t] = acc[m];
    }
}

// ---------------------------------------------------------------------------
// K0b: combine -> tanh -> softmax_m -> ci -> a2. grid B, 768 thr
// ---------------------------------------------------------------------------
__global__ __launch_bounds__(768) void k_audio2a(
    const float* __restrict__ causal, const float* __restrict__ audio,
    const float* __restrict__ pf, const float* __restrict__ pf2,
    const float* __restrict__ bf, const float* __restrict__ bf2,
    const float* __restrict__ cparam, float* __restrict__ a2) {
    int b = blockIdx.x;
    int t = threadIdx.x;
    float cp = 1.0f / (1.0f + __expf(-cparam[0]));
    float tf[MM], f2[MM];
    float mx = -1e30f;
    #pragma unroll
    for (int m = 0; m < MM; ++m) {
        float acc = bf[t];
        float s2 = bf2[0];
        #pragma unroll
        for (int kc = 0; kc < 3; ++kc) {
            acc += pf[(((size_t)b * 3 + kc) * MM + m) * DD + t];
            s2 += pf2[(b * 3 + kc) * MM + m];
        }
        tf[m] = fast_tanh(acc);
        f2[m] = s2;
        mx = fmaxf(mx, tf[m]);
    }
    float s = 0.f;
    #pragma unroll
    for (int m = 0; m < MM; ++m) { tf[m] = __expf(tf[m] - mx); s += tf[m]; }
    float inv = 1.0f / s;
    float ci = 0.f;
    #pragma unroll
    for (int m = 0; m < MM; ++m)
        ci += f2[m] * (tf[m] * inv) * causal[((size_t)b * MM + m) * DD + t];
    a2[(size_t)b * DD + t] = cp * ci + audio[(size_t)b * DD + t];
}

// ---------------------------------------------------------------------------
// K0c: pa/af GEMVs; also zeroes colsum. grid (24,2), 256 threads.
// ---------------------------------------------------------------------------
__global__ __launch_bounds__(256) void k_audio2b(
    const float* __restrict__ a2,
    const float* __restrict__ Waa, const float* __restrict__ baa,
    const float* __restrict__ Wa, const float* __restrict__ ba,
    float* __restrict__ pa, float* __restrict__ af, float* __restrict__ colsum) {
    int gid0 = (blockIdx.y * 24 + blockIdx.x) * 256 + threadIdx.x;
    for (int i = gid0; i < BB * TT * DD; i += 48 * 256) colsum[i] = 0.f;
    __shared__ float a2s[16][DD + 4];
    int sel = blockIdx.y;
    const float* W = sel ? Wa : Waa;
    int t = threadIdx.x;
    int c = blockIdx.x * 32 + (t & 31);
    int slot = t >> 5;
    float bias = sel ? ba[c] : baa[c];
    #pragma unroll
    for (int g = 0; g < 2; ++g) {
        if (g) __syncthreads();
        for (int i = t; i < 16 * DD; i += 256)
            a2s[i / DD][i % DD] = a2[(size_t)(g * 16 + i / DD) * DD + i % DD];
        __syncthreads();
        float acc0 = 0.f, acc1 = 0.f;
        #pragma unroll 8
        for (int k = 0; k < DD; ++k) {
            float wv = W[(size_t)k * DD + c];
            acc0 = fmaf(a2s[slot][k], wv, acc0);
            acc1 = fmaf(a2s[slot + 8][k], wv, acc1);
        }
        int b0 = g * 16 + slot, b1 = b0 + 8;
        if (sel == 0) {
            pa[(size_t)b0 * DD + c] = fast_tanh(acc0 + bias);
            pa[(size_t)b1 * DD + c] = fast_tanh(acc1 + bias);
        } else {
            af[(size_t)b0 * DD + c] = fmaxf(acc0 + bias, 0.f);
            af[(size_t)b1 * DD + c] = fmaxf(acc1 + bias, 0.f);
        }
    }
}

// ---------------------------------------------------------------------------
// K2: pvh = f16(tanh(visb @ Wht^T + bav)); BK=32 double-buffer, counted
// vmcnt(4), 33KB LDS -> 4 blocks/CU (16 waves/CU for TLP latency hiding).
// ---------------------------------------------------------------------------
__global__ __launch_bounds__(256, 4) void k_pv_mfma(
    const unsigned short* __restrict__ visb, const unsigned short* __restrict__ Wht,
    const float* __restrict__ bav, const float* __restrict__ pa,
    unsigned short* __restrict__ pvh, float* __restrict__ colsum)
{
    __shared__ unsigned short SH[4][4096];   // A0,A1,B0,B1: each 128x32 bf16
    __shared__ float cred[256];
    int wg = blockIdx.x;
    int lin = (wg & 7) * 294 + (wg >> 3);   // bijective XCD swizzle (2352%8==0)
    int mt = lin / 6, nt = lin % 6;
    int i0 = mt * 128, n0 = nt * 128;
    int t = threadIdx.x, w = t >> 6, l = t & 63;
    int wm = (w >> 1) * 64, wn = (w & 1) * 64;

    float4v zero4 = {0.f, 0.f, 0.f, 0.f};
    float4v acc[4][4];
    #pragma unroll
    for (int a = 0; a < 4; ++a)
        #pragma unroll
        for (int b = 0; b < 4; ++b) acc[a][b] = zero4;

    // staging: wave w, call j in {0,1} covers rows (w*2+j)*16 + (l>>2),
    // lane chunk (l&3) holds source chunk (l&3)^(row&3)  (XOR both sides)
    int srow[2], scs[2];
    #pragma unroll
    for (int j = 0; j < 2; ++j) {
        int row = (w * 2 + j) * 16 + (l >> 2);
        srow[j] = row;
        scs[j] = (l & 3) ^ (row & 3);
    }

#define STAGE(bb, wnd_)                                                          \
    {                                                                            \
        int kw_ = (wnd_) * 32;                                                   \
        _Pragma("unroll")                                                        \
        for (int j = 0; j < 2; ++j) {                                            \
            size_t aoff_ = (size_t)(i0 + srow[j]) * DD + kw_ + scs[j] * 8;       \
            __builtin_amdgcn_global_load_lds(                                    \
                (const __attribute__((address_space(1))) unsigned int*)(visb + aoff_), \
                (__attribute__((address_space(3))) unsigned int*)&SH[bb][(w * 2 + j) * 512], \
                16, 0, 0);                                                       \
            size_t boff_ = (size_t)(n0 + srow[j]) * DD + kw_ + scs[j] * 8;       \
            __builtin_amdgcn_global_load_lds(                                    \
                (const __attribute__((address_space(1))) unsigned int*)(Wht + boff_), \
                (__attribute__((address_space(3))) unsigned int*)&SH[2 + bb][(w * 2 + j) * 512], \
                16, 0, 0);                                                       \
        }                                                                        \
    }

    STAGE(0, 0);
    for (int wnd = 0; wnd < 24; ++wnd) {
        int cur = wnd & 1;
        if (wnd < 23) {
            STAGE(cur ^ 1, wnd + 1);                       // 8 outstanding
            asm volatile("s_waitcnt vmcnt(4)" ::: "memory");  // window-w landed
        } else {
            asm volatile("s_waitcnt vmcnt(0)" ::: "memory");
        }
        __builtin_amdgcn_s_barrier();
        __builtin_amdgcn_s_setprio(1);
        {
            short8v ahf[4], bhf[4];
            int cA = l >> 4;
            #pragma unroll
            for (int mr = 0; mr < 4; ++mr) {
                int row = wm + mr * 16 + (l & 15);
                ahf[mr] = *(const short8v*)&SH[cur][row * 32 + ((cA ^ (row & 3)) * 8)];
            }
            #pragma unroll
            for (int nc = 0; nc < 4; ++nc) {
                int row = wn + nc * 16 + (l & 15);
                bhf[nc] = *(const short8v*)&SH[2 + cur][row * 32 + ((cA ^ (row & 3)) * 8)];
            }
            #pragma unroll
            for (int mr = 0; mr < 4; ++mr)
                #pragma unroll
                for (int nc = 0; nc < 4; ++nc)
                    acc[mr][nc] = __builtin_amdgcn_mfma_f32_16x16x32_bf16(
                        ahf[mr], bhf[nc], acc[mr][nc], 0, 0, 0);
        }
        __builtin_amdgcn_s_setprio(0);
        asm volatile("s_waitcnt lgkmcnt(0)" ::: "memory");
        __builtin_amdgcn_sched_barrier(0);
        __builtin_amdgcn_s_barrier();    // buf[cur] fully read before re-stage
    }
#undef STAGE
    // ---- epilogue: C tile (f16, XOR-swizzled) in the full 32KB SH ----
    unsigned short* Cl = &SH[0][0];
    if (t < 256) cred[t] = 0.f;
    __syncthreads();
    int bt0 = i0 / PP;
    int btbound = (bt0 + 1) * PP;       // first row of next bt
    #pragma unroll
    for (int nc = 0; nc < 4; ++nc) {
        int cl = wn + nc * 16 + (l & 15);
        int col = n0 + cl;
        float bias = bav[col];
        #pragma unroll
        for (int mr = 0; mr < 4; ++mr) {
            int lr0 = wm + mr * 16 + ((l >> 4) << 2);
            int row0 = i0 + lr0;
            int bq = row0 / (TT * PP);
            float pav = pa[(size_t)bq * DD + col];
            float esum = 0.f;
            #pragma unroll
            for (int v = 0; v < 4; ++v) {
                unsigned short pb = f2h(fast_tanh(acc[mr][nc][v] + bias));
                int lr = lr0 + v;
                int boff = lr * 256 + ((cl * 2) ^ ((lr & 7) << 4));
                *(unsigned short*)((char*)Cl + boff) = pb;
                esum += __expf(h2f(pb) * pav);
            }
            int btg = (row0 >= btbound) ? 1 : 0;
            atomicAdd(&cred[btg * 128 + cl], esum);
        }
    }
    __syncthreads();
    // coalesced pvh store: 4 lanes x 16B = one 64B line per row per instr
    #pragma unroll
    for (int rb = 0; rb < 2; ++rb) {
        int lr = (t >> 2) + rb * 64;
        size_t grow = (size_t)(i0 + lr) * DD + n0;
        #pragma unroll
        for (int q = 0; q < 4; ++q) {
            int ch = (t & 3) + q * 4;
            int boff = lr * 256 + ((ch * 16) ^ ((lr & 7) << 4));
            uint4 val = *(uint4*)((char*)Cl + boff);
            *(uint4*)(pvh + grow + ch * 8) = val;
        }
    }
    if (t < 256) {
        int btg = t >> 7, cl = t & 127;
        if (btg == 0 || btbound < i0 + 128)
            atomicAdd(&colsum[(size_t)(bt0 + btg) * DD + n0 + cl], cred[t]);
    }
}

// ---------------------------------------------------------------------------
// K3a: partial patch sums per (bt, col-quarter). grid (256,4), 768 thr.
// patch_q[bt][p][qd] = sum over 192 cols of sattn  (deterministic writer)
// ---------------------------------------------------------------------------
__global__ __launch_bounds__(768) void k_patchsum(
    const unsigned short* __restrict__ pvh, const float* __restrict__ pa,
    const float* __restrict__ colsum, float* __restrict__ patch_q) {
    int bt = blockIdx.x, qd = blockIdx.y;
    int b = bt >> 3;
    size_t base = (size_t)bt * PP * DD;
    int c0 = qd * 192;
    __shared__ float2 pi[192];
    int t = threadIdx.x;
    if (t < 192) {
        int col = c0 + t;
        pi[t] = make_float2(pa[(size_t)b * DD + col],
                            1.0f / colsum[(size_t)bt * DD + col]);
    }
    __syncthreads();
    int wv = t >> 6, l = t & 63;
    for (int p = wv; p < PP; p += 12) {
        float sum = 0.f;
        if (l < 48) {
            const uint2* rv = (const uint2*)(pvh + base + (size_t)p * DD + c0);
            uint2 v = rv[l];
            int c = l * 4;
            float2 q0 = pi[c], q1 = pi[c + 1], q2 = pi[c + 2], q3 = pi[c + 3];
            sum = __expf(h2f((unsigned short)(v.x & 0xFFFFu)) * q0.x) * q0.y
                + __expf(h2f((unsigned short)(v.x >> 16)) * q1.x) * q1.y
                + __expf(h2f((unsigned short)(v.y & 0xFFFFu)) * q2.x) * q2.y
                + __expf(h2f((unsigned short)(v.y >> 16)) * q3.x) * q3.y;
        }
        #pragma unroll
        for (int o = 32; o > 0; o >>= 1) sum += __shfl_down(sum, o);
        if (l == 0) patch_q[((size_t)bt * PP + p) * 4 + qd] = sum;
    }
}

// ---------------------------------------------------------------------------
// K3b: masked sums (+ local rank-select from patch_q). grid (256 bt, 4 qd);
// 768 thr = 192 cols x 4 p-groups (49 rows each).
// ---------------------------------------------------------------------------
__global__ __launch_bounds__(768) void k_masked(
    const unsigned short* __restrict__ pvh, const unsigned short* __restrict__ visb,
    const void* __restrict__ rmask, const int* __restrict__ mode_p,
    const float* __restrict__ pa, const float* __restrict__ colsum,
    const float* __restrict__ patch_q,
    float* __restrict__ sav, float* __restrict__ vpt) {
    int bt = blockIdx.x;
    int qd = blockIdx.y;
    int b = bt >> 3;
    size_t base = (size_t)bt * PP * DD;
    __shared__ float patch[PP];
    __shared__ unsigned char spa[PP];
    __shared__ float red_s[4][192];
    __shared__ float red_v[4][192];
    int t = threadIdx.x;
    if (t < PP) {
        float4 v = *(const float4*)&patch_q[((size_t)bt * PP + t) * 4];
        patch[t] = ((v.x + v.y) + v.z) + v.w;   // fixed order: deterministic
    }
    __syncthreads();
    if (t < PP) {
        float x = patch[t];
        int c = 0;
        for (int q = 0; q < PP; ++q) c += (patch[q] <= x) ? 1 : 0;
        spa[t] = (c <= NIDX) ? 1 : 0;
    }
    int pg = t / 192;
    int c = t - pg * 192;
    int col = qd * 192 + c;
    int p0 = pg * 49, p1 = p0 + 49;
    float pav = pa[(size_t)b * DD + col];
    float inv = 1.0f / colsum[(size_t)bt * DD + col];
    __syncthreads();
    const unsigned short* pvb = pvh + base + col;
    const unsigned short* vib = visb + base + col;
    float sava = 0.f, vpa = 0.f;
    int mode = *mode_p;
    if (mode == 0) {
        const int* mb = (const int*)rmask + base + col;
        #pragma unroll 7
        for (int p = p0; p < p1; ++p) {
            float pvv = h2f(pvb[(size_t)p * DD]);
            float sa = __expf(pvv * pav) * inv;
            bool km = !(spa[p] && (mb[(size_t)p * DD] != 0));
            if (km) { sava = fmaf(sa, pvv, sava); vpa = fmaf(sa, bf2f(vib[(size_t)p * DD]), vpa); }
        }
    } else if (mode == 1) {
        const float* mb = (const float*)rmask + base + col;
        #pragma unroll 7
        for (int p = p0; p < p1; ++p) {
            float pvv = h2f(pvb[(size_t)p * DD]);
            float sa = __expf(pvv * pav) * inv;
            bool km = !(spa[p] && (mb[(size_t)p * DD] != 0.f));
            if (km) { sava = fmaf(sa, pvv, sava); vpa = fmaf(sa, bf2f(vib[(size_t)p * DD]), vpa); }
        }
    } else {
        const unsigned char* mb = (const unsigned char*)rmask + base + col;
        #pragma unroll 7
        for (int p = p0; p < p1; ++p) {
            float pvv = h2f(pvb[(size_t)p * DD]);
            float sa = __expf(pvv * pav) * inv;
            bool km = !(spa[p] && (mb[(size_t)p * DD] != 0));
            if (km) { sava = fmaf(sa, pvv, sava); vpa = fmaf(sa, bf2f(vib[(size_t)p * DD]), vpa); }
        }
    }
    red_s[pg][c] = sava;
    red_v[pg][c] = vpa;
    __syncthreads();
    if (t < 192) {
        int col2 = qd * 192 + t;
        sav[(size_t)bt * DD + col2] = red_s[0][t] + red_s[1][t] + red_s[2][t] + red_s[3][t];
        vpt[(size_t)bt * DD + col2] = red_v[0][t] + red_v[1][t] + red_v[2][t] + red_v[3][t];
    }
}

// ---------------------------------------------------------------------------
// K4a: temporal softmax -> vp[B][D]. grid B, 768 threads
// ---------------------------------------------------------------------------
__global__ __launch_bounds__(768) void k_tail_a(
    const float* __restrict__ sav, const float* __restrict__ vpt,
    const float* __restrict__ pa, float* __restrict__ vp) {
    int b = blockIdx.x;
    int t = threadIdx.x;
    float pav = pa[(size_t)b * DD + t];
    float x[TT];
    float mx = -1e30f;
    #pragma unroll
    for (int k = 0; k < TT; ++k) {
        x[k] = sav[((size_t)b * TT + k) * DD + t] * pav;
        mx = fmaxf(mx, x[k]);
    }
    float s = 0.f;
    #pragma unroll
    for (int k = 0; k < TT; ++k) { x[k] = __expf(x[k] - mx); s += x[k]; }
    float inv = 1.0f / s;
    float acc = 0.f;
    #pragma unroll
    for (int k = 0; k < TT; ++k)
        acc += x[k] * inv * vpt[((size_t)b * TT + k) * DD + t];
    vp[(size_t)b * DD + t] = acc;
}

// ---------------------------------------------------------------------------
// K4b: h = relu(vp@Wv+bv) + af. grid 24, 256 threads
// ---------------------------------------------------------------------------
__global__ __launch_bounds__(256) void k_tail_b(
    const float* __restrict__ vp, const float* __restrict__ af,
    const float* __restrict__ Wv, const float* __restrict__ bv,
    float* __restrict__ h) {
    __shared__ float vs[16][DD + 4];
    int t = threadIdx.x;
    int c = blockIdx.x * 32 + (t & 31);
    int slot = t >> 5;
    float bias = bv[c];
    #pragma unroll
    for (int g = 0; g < 2; ++g) {
        if (g) __syncthreads();
        for (int i = t; i < 16 * DD; i += 256)
            vs[i / DD][i % DD] = vp[(size_t)(g * 16 + i / DD) * DD + i % DD];
        __syncthreads();
        float acc0 = 0.f, acc1 = 0.f;
        #pragma unroll 8
        for (int k = 0; k < DD; ++k) {
            float wv = Wv[(size_t)k * DD + c];
            acc0 = fmaf(vs[slot][k], wv, acc0);
            acc1 = fmaf(vs[slot + 8][k], wv, acc1);
        }
        int b0 = g * 16 + slot, b1 = b0 + 8;
        h[(size_t)b0 * DD + c] = fmaxf(acc0 + bias, 0.f) + af[(size_t)b0 * DD + c];
        h[(size_t)b1 * DD + c] = fmaxf(acc1 + bias, 0.f) + af[(size_t)b1 * DD + c];
    }
}

// ---------------------------------------------------------------------------
// K4c: logits = h@Wc + bc. grid 13, 256 threads
// ---------------------------------------------------------------------------
__global__ __launch_bounds__(256) void k_tail_c(
    const float* __restrict__ h, const float* __restrict__ Wc,
    const float* __restrict__ bc, float* __restrict__ out) {
    int t = threadIdx.x;
    int c = blockIdx.x * 8 + (t & 7);
    int b = t >> 3;
    if (c >= NCLS) return;
    float acc = bc[c];
    #pragma unroll 8
    for (int k = 0; k < DD; ++k)
        acc = fmaf(h[(size_t)b * DD + k], Wc[(size_t)k * NCLS + c], acc);
    out[(size_t)b * NCLS + c] = acc;
}

// ---------------------------------------------------------------------------
extern "C" void kernel_launch(void* const* d_in, const int* in_sizes, int n_in,
                              void* d_out, int out_size, void* d_ws, size_t ws_size,
                              hipStream_t stream) {
    const float* visual = (const float*)d_in[0];
    const float* audio  = (const float*)d_in[1];
    const float* causal = (const float*)d_in[2];
    const void*  rmask  = d_in[3];
    const float* Wa   = (const float*)d_in[4];
    const float* ba   = (const float*)d_in[5];
    const float* Wv   = (const float*)d_in[6];
    const float* bv   = (const float*)d_in[7];
    const float* Waa  = (const float*)d_in[8];
    const float* baa  = (const float*)d_in[9];
    const float* Wav  = (const float*)d_in[10];
    const float* bav  = (const float*)d_in[11];
    const float* Wf   = (const float*)d_in[12];
    const float* bf   = (const float*)d_in[13];
    const float* Wf2  = (const float*)d_in[14];
    const float* bf2  = (const float*)d_in[15];
    const float* Wc   = (const float*)d_in[16];
    const float* bc   = (const float*)d_in[17];
    const float* cpar = (const float*)d_in[18];
    float* out = (float*)d_out;

    const size_t NE = (size_t)BB * TT * PP * DD;   // 38,535,168
    unsigned short* Wht = (unsigned short*)d_ws;                   // D*D bf16
    float* pfreg = (float*)(Wht + (size_t)DD * DD);                // overlay region
    float* colsum = pfreg;                                         // 196608 f
    float* savw  = colsum + (size_t)BB * TT * DD;                  // 196608 f
    float* vptw  = savw + (size_t)BB * TT * DD;                    // 196608 f
    float* vpw   = vptw + (size_t)BB * TT * DD;                    // 24576 f
    float* hw    = vpw + (size_t)BB * DD;                          // 24576 f
    float* pf    = pfreg;                                          // alias
    float* pf2   = pfreg + (size_t)BB * 3 * MM * DD;               // 960 f (pad 1024)
    float* a2w   = pf2 + 1024;                                     // B*D
    float* paw   = a2w + (size_t)BB * DD;                          // B*D
    float* afw   = paw + (size_t)BB * DD;                          // B*D
    int*   modew = (int*)(afw + (size_t)BB * DD);                  // pad 16
    unsigned short* visb = (unsigned short*)(modew + 16);          // NE bf16
    unsigned short* pvh  = visb + NE;                              // NE f16
    float* patchq = (float*)(pvh + NE);                            // 256*196*4 f

    k_prep_all<<<1696, 768, 0, stream>>>(visual, visb, (const unsigned int*)rmask,
                                         modew, Wav, Wht, causal, Wf, Wf2, pf, pf2);
    k_audio2a<<<BB, 768, 0, stream>>>(causal, audio, pf, pf2, bf, bf2, cpar, a2w);
    k_audio2b<<<dim3(24, 2), 256, 0, stream>>>(a2w, Waa, baa, Wa, ba, paw, afw, colsum);
    k_pv_mfma<<<2352, 256, 0, stream>>>(visb, Wht, bav, paw, pvh, colsum);
    k_patchsum<<<dim3(BB * TT, 4), 768, 0, stream>>>(pvh, paw, colsum, patchq);
    k_masked<<<dim3(BB * TT, 4), 768, 0, stream>>>(pvh, visb, rmask, modew, paw,
                                                   colsum, patchq, savw, vptw);
    k_tail_a<<<BB, 768, 0, stream>>>(savw, vptw, paw, vpw);
    k_tail_b<<<24, 256, 0, stream>>>(vpw, afw, Wv, bv, hw);
    k_tail_c<<<13, 256, 0, stream>>>(hw, Wc, bc, out);
}

// Round 13
// 478.809 us; speedup vs baseline: 1.0644x; 1.0644x over previous
//
#include <hip/hip_runtime.h>
#include <hip/hip_bf16.h>
#include <hip/hip_fp16.h>
#include <math.h>

#define BB 32
#define TT 8
#define PP 196
#define DD 768
#define MM 10
#define NCLS 100
#define NIDX 98

typedef __attribute__((ext_vector_type(8))) short short8v;
typedef __attribute__((ext_vector_type(4))) float float4v;

__device__ __forceinline__ float fast_tanh(float x) {
    float e = __expf(2.0f * x);
    return 1.0f - 2.0f / (e + 1.0f);
}
__device__ __forceinline__ unsigned short f2bf(float x) {
    __hip_bfloat16 h = __float2bfloat16(x);
    return *(unsigned short*)&h;
}
__device__ __forceinline__ float bf2f(unsigned short h) {
    return __uint_as_float(((unsigned)h) << 16);
}
__device__ __forceinline__ unsigned short f2h(float x) {
    __half h = __float2half(x);
    return *(unsigned short*)&h;
}
__device__ __forceinline__ float h2f(unsigned short u) {
    __half h = *(__half*)&u;
    return __half2float(h);
}

// ---------------------------------------------------------------------------
// K-1 fused prep: blocks [0,1024) vis f32->bf16 (+mask detect in block 0);
// blocks [1024,1600) Wav transpose+rtne; blocks [1600,1696) feats partials.
// ---------------------------------------------------------------------------
__global__ __launch_bounds__(768) void k_prep_all(
    const float* __restrict__ vis, unsigned short* __restrict__ visb,
    const unsigned int* __restrict__ rm, int* __restrict__ mode,
    const float* __restrict__ Wav, unsigned short* __restrict__ Wht,
    const float* __restrict__ causal, const float* __restrict__ Wf,
    const float* __restrict__ Wf2,
    float* __restrict__ pf, float* __restrict__ pf2) {
    int t = threadIdx.x;
    int bid = blockIdx.x;
    if (bid < 1024) {
        const size_t NC = (size_t)BB * TT * PP * DD / 8;   // uint4 chunks
        size_t gid = (size_t)bid * 768 + t;
        for (size_t i = gid; i < NC; i += 1024 * 768) {
            const float4* s = (const float4*)(vis + i * 8);
            float4 x = s[0], y = s[1];
            __hip_bfloat162 h;
            unsigned int u0, u1, u2, u3;
            h = __float22bfloat162_rn(make_float2(x.x, x.y)); u0 = *(unsigned int*)&h;
            h = __float22bfloat162_rn(make_float2(x.z, x.w)); u1 = *(unsigned int*)&h;
            h = __float22bfloat162_rn(make_float2(y.x, y.y)); u2 = *(unsigned int*)&h;
            h = __float22bfloat162_rn(make_float2(y.z, y.w)); u3 = *(unsigned int*)&h;
            uint4 o; o.x = u0; o.y = u1; o.z = u2; o.w = u3;
            ((uint4*)visb)[i] = o;
        }
        if (bid == 0) {
            __shared__ int f_ni, f_nf;
            if (t == 0) { f_ni = 0; f_nf = 0; }
            __syncthreads();
            int ni = 0, nf = 0;
            for (int i = t; i < 16384; i += 768) {
                unsigned int v = rm[i];
                ni |= (v > 1u) ? 1 : 0;
                nf |= (v != 0u && v != 0x3F800000u) ? 1 : 0;
            }
            if (ni) atomicOr(&f_ni, 1);
            if (nf) atomicOr(&f_nf, 1);
            __syncthreads();
            if (t == 0) *mode = f_ni ? (f_nf ? 2 : 1) : 0;
        }
    } else if (bid < 1600) {
        __shared__ float tile[32][33];
        int bb = bid - 1024;
        int bn = (bb % 24) * 32;
        int bk = (bb / 24) * 32;
        if (t < 256) {
            int tx = t & 31, ty = t >> 5;
            #pragma unroll
            for (int i = 0; i < 4; ++i)
                tile[ty + i * 8][tx] = Wav[(size_t)(bk + ty + i * 8) * DD + bn + tx];
        }
        __syncthreads();
        if (t < 256) {
            int tx = t & 31, ty = t >> 5;
            #pragma unroll
            for (int i = 0; i < 4; ++i) {
                int n = bn + ty + i * 8, k = bk + tx;
                Wht[(size_t)n * DD + k] = f2bf(tile[tx][ty + i * 8]);
            }
        }
    } else {
        __shared__ float cs[MM][256];
        __shared__ float red[MM][12];
        int bb = bid - 1600;
        int b = bb % 32, kc = bb / 32;
        int k0 = kc * 256;
        for (int i = t; i < MM * 256; i += 768)
            cs[i >> 8][i & 255] = causal[((size_t)b * MM + (i >> 8)) * DD + k0 + (i & 255)];
        __syncthreads();
        int wave = t >> 6, lane = t & 63;
        float w2v = (t < 256) ? Wf2[k0 + t] : 0.f;
        #pragma unroll
        for (int m = 0; m < MM; ++m) {
            float p = (t < 256) ? cs[m][t] * w2v : 0.f;
            #pragma unroll
            for (int o = 32; o > 0; o >>= 1) p += __shfl_down(p, o);
            if (lane == 0) red[m][wave] = p;
        }
        __syncthreads();
        if (t < MM) {
            float s = 0.f;
            #pragma unroll
            for (int wv = 0; wv < 4; ++wv) s += red[t][wv];
            pf2[(b * 3 + kc) * MM + t] = s;
        }
        float acc[MM];
        #pragma unroll
        for (int m = 0; m < MM; ++m) acc[m] = 0.f;
        #pragma unroll 4
        for (int k = 0; k < 256; ++k) {
            float wv = Wf[(size_t)(k0 + k) * DD + t];
            #pragma unroll
            for (int m = 0; m < MM; ++m) acc[m] = fmaf(cs[m][k], wv, acc[m]);
        }
        #pragma unroll
        for (int m = 0; m < MM; ++m)
            pf[(((size_t)b * 3 + kc) * MM + m) * DD + t] = acc[m];
    }
}

// ---------------------------------------------------------------------------
// K0b: combine -> tanh -> softmax_m -> ci -> a2. grid B, 768 thr
// ---------------------------------------------------------------------------
__global__ __launch_bounds__(768) void k_audio2a(
    const float* __restrict__ causal, const float* __restrict__ audio,
    const float* __restrict__ pf, const float* __restrict__ pf2,
    const float* __restrict__ bf, const float* __restrict__ bf2,
    const float* __restrict__ cparam, float* __restrict__ a2) {
    int b = blockIdx.x;
    int t = threadIdx.x;
    float cp = 1.0f / (1.0f + __expf(-cparam[0]));
    float tf[MM], f2[MM];
    float mx = -1e30f;
    #pragma unroll
    for (int m = 0; m < MM; ++m) {
        float acc = bf[t];
        float s2 = bf2[0];
        #pragma unroll
        for (int kc = 0; kc < 3; ++kc) {
            acc += pf[(((size_t)b * 3 + kc) * MM + m) * DD + t];
            s2 += pf2[(b * 3 + kc) * MM + m];
        }
        tf[m] = fast_tanh(acc);
        f2[m] = s2;
        mx = fmaxf(mx, tf[m]);
    }
    float s = 0.f;
    #pragma unroll
    for (int m = 0; m < MM; ++m) { tf[m] = __expf(tf[m] - mx); s += tf[m]; }
    float inv = 1.0f / s;
    float ci = 0.f;
    #pragma unroll
    for (int m = 0; m < MM; ++m)
        ci += f2[m] * (tf[m] * inv) * causal[((size_t)b * MM + m) * DD + t];
    a2[(size_t)b * DD + t] = cp * ci + audio[(size_t)b * DD + t];
}

// ---------------------------------------------------------------------------
// K0c: pa/af GEMVs; also zeroes colsum. grid (24,2), 256 threads.
// ---------------------------------------------------------------------------
__global__ __launch_bounds__(256) void k_audio2b(
    const float* __restrict__ a2,
    const float* __restrict__ Waa, const float* __restrict__ baa,
    const float* __restrict__ Wa, const float* __restrict__ ba,
    float* __restrict__ pa, float* __restrict__ af, float* __restrict__ colsum) {
    int gid0 = (blockIdx.y * 24 + blockIdx.x) * 256 + threadIdx.x;
    for (int i = gid0; i < BB * TT * DD; i += 48 * 256) colsum[i] = 0.f;
    __shared__ float a2s[16][DD + 4];
    int sel = blockIdx.y;
    const float* W = sel ? Wa : Waa;
    int t = threadIdx.x;
    int c = blockIdx.x * 32 + (t & 31);
    int slot = t >> 5;
    float bias = sel ? ba[c] : baa[c];
    #pragma unroll
    for (int g = 0; g < 2; ++g) {
        if (g) __syncthreads();
        for (int i = t; i < 16 * DD; i += 256)
            a2s[i / DD][i % DD] = a2[(size_t)(g * 16 + i / DD) * DD + i % DD];
        __syncthreads();
        float acc0 = 0.f, acc1 = 0.f;
        #pragma unroll 8
        for (int k = 0; k < DD; ++k) {
            float wv = W[(size_t)k * DD + c];
            acc0 = fmaf(a2s[slot][k], wv, acc0);
            acc1 = fmaf(a2s[slot + 8][k], wv, acc1);
        }
        int b0 = g * 16 + slot, b1 = b0 + 8;
        if (sel == 0) {
            pa[(size_t)b0 * DD + c] = fast_tanh(acc0 + bias);
            pa[(size_t)b1 * DD + c] = fast_tanh(acc1 + bias);
        } else {
            af[(size_t)b0 * DD + c] = fmaxf(acc0 + bias, 0.f);
            af[(size_t)b1 * DD + c] = fmaxf(acc1 + bias, 0.f);
        }
    }
}

// ---------------------------------------------------------------------------
// K2: pvh = f16(tanh(visb @ Wht^T + bav)); BK=32 double-buffer, counted
// vmcnt(4), 4 blocks/CU. Swizzle swz(row)=(row>>1)&3: 2-way bank alias (free).
// ---------------------------------------------------------------------------
__global__ __launch_bounds__(256, 4) void k_pv_mfma(
    const unsigned short* __restrict__ visb, const unsigned short* __restrict__ Wht,
    const float* __restrict__ bav, const float* __restrict__ pa,
    unsigned short* __restrict__ pvh, float* __restrict__ colsum)
{
    __shared__ unsigned short SH[4][4096];   // A0,A1,B0,B1: each 128x32 bf16
    __shared__ float cred[256];
    int wg = blockIdx.x;
    int lin = (wg & 7) * 294 + (wg >> 3);   // bijective XCD swizzle (2352%8==0)
    int mt = lin / 6, nt = lin % 6;
    int i0 = mt * 128, n0 = nt * 128;
    int t = threadIdx.x, w = t >> 6, l = t & 63;
    int wm = (w >> 1) * 64, wn = (w & 1) * 64;

    float4v zero4 = {0.f, 0.f, 0.f, 0.f};
    float4v acc[4][4];
    #pragma unroll
    for (int a = 0; a < 4; ++a)
        #pragma unroll
        for (int b = 0; b < 4; ++b) acc[a][b] = zero4;

    // staging: wave w, call j in {0,1} covers rows (w*2+j)*16 + (l>>2),
    // lane chunk (l&3) holds source chunk (l&3)^((row>>1)&3)
    int srow[2], scs[2];
    #pragma unroll
    for (int j = 0; j < 2; ++j) {
        int row = (w * 2 + j) * 16 + (l >> 2);
        srow[j] = row;
        scs[j] = (l & 3) ^ ((row >> 1) & 3);
    }

#define STAGE(bb, wnd_)                                                          \
    {                                                                            \
        int kw_ = (wnd_) * 32;                                                   \
        _Pragma("unroll")                                                        \
        for (int j = 0; j < 2; ++j) {                                            \
            size_t aoff_ = (size_t)(i0 + srow[j]) * DD + kw_ + scs[j] * 8;       \
            __builtin_amdgcn_global_load_lds(                                    \
                (const __attribute__((address_space(1))) unsigned int*)(visb + aoff_), \
                (__attribute__((address_space(3))) unsigned int*)&SH[bb][(w * 2 + j) * 512], \
                16, 0, 0);                                                       \
            size_t boff_ = (size_t)(n0 + srow[j]) * DD + kw_ + scs[j] * 8;       \
            __builtin_amdgcn_global_load_lds(                                    \
                (const __attribute__((address_space(1))) unsigned int*)(Wht + boff_), \
                (__attribute__((address_space(3))) unsigned int*)&SH[2 + bb][(w * 2 + j) * 512], \
                16, 0, 0);                                                       \
        }                                                                        \
    }

    STAGE(0, 0);
    for (int wnd = 0; wnd < 24; ++wnd) {
        int cur = wnd & 1;
        if (wnd < 23) {
            STAGE(cur ^ 1, wnd + 1);                       // 8 outstanding
            asm volatile("s_waitcnt vmcnt(4)" ::: "memory");  // window-w landed
        } else {
            asm volatile("s_waitcnt vmcnt(0)" ::: "memory");
        }
        __builtin_amdgcn_s_barrier();
        __builtin_amdgcn_s_setprio(1);
        {
            short8v ahf[4], bhf[4];
            int cA = l >> 4;
            #pragma unroll
            for (int mr = 0; mr < 4; ++mr) {
                int row = wm + mr * 16 + (l & 15);
                ahf[mr] = *(const short8v*)&SH[cur][row * 32 + ((cA ^ ((row >> 1) & 3)) * 8)];
            }
            #pragma unroll
            for (int nc = 0; nc < 4; ++nc) {
                int row = wn + nc * 16 + (l & 15);
                bhf[nc] = *(const short8v*)&SH[2 + cur][row * 32 + ((cA ^ ((row >> 1) & 3)) * 8)];
            }
            #pragma unroll
            for (int mr = 0; mr < 4; ++mr)
                #pragma unroll
                for (int nc = 0; nc < 4; ++nc)
                    acc[mr][nc] = __builtin_amdgcn_mfma_f32_16x16x32_bf16(
                        ahf[mr], bhf[nc], acc[mr][nc], 0, 0, 0);
        }
        __builtin_amdgcn_s_setprio(0);
        asm volatile("s_waitcnt lgkmcnt(0)" ::: "memory");
        __builtin_amdgcn_sched_barrier(0);
        __builtin_amdgcn_s_barrier();    // buf[cur] fully read before re-stage
    }
#undef STAGE
    // ---- epilogue: C tile (f16, XOR-swizzled) in the full 32KB SH ----
    unsigned short* Cl = &SH[0][0];
    if (t < 256) cred[t] = 0.f;
    __syncthreads();
    int bt0 = i0 / PP;
    int btbound = (bt0 + 1) * PP;       // first row of next bt
    #pragma unroll
    for (int nc = 0; nc < 4; ++nc) {
        int cl = wn + nc * 16 + (l & 15);
        int col = n0 + cl;
        float bias = bav[col];
        #pragma unroll
        for (int mr = 0; mr < 4; ++mr) {
            int lr0 = wm + mr * 16 + ((l >> 4) << 2);
            int row0 = i0 + lr0;
            int bq = row0 / (TT * PP);
            float pav = pa[(size_t)bq * DD + col];
            float esum = 0.f;
            #pragma unroll
            for (int v = 0; v < 4; ++v) {
                unsigned short pb = f2h(fast_tanh(acc[mr][nc][v] + bias));
                int lr = lr0 + v;
                int boff = lr * 256 + ((cl * 2) ^ ((lr & 7) << 4));
                *(unsigned short*)((char*)Cl + boff) = pb;
                esum += __expf(h2f(pb) * pav);
            }
            int btg = (row0 >= btbound) ? 1 : 0;
            atomicAdd(&cred[btg * 128 + cl], esum);
        }
    }
    __syncthreads();
    // coalesced pvh store: 4 lanes x 16B = one 64B line per row per instr
    #pragma unroll
    for (int rb = 0; rb < 2; ++rb) {
        int lr = (t >> 2) + rb * 64;
        size_t grow = (size_t)(i0 + lr) * DD + n0;
        #pragma unroll
        for (int q = 0; q < 4; ++q) {
            int ch = (t & 3) + q * 4;
            int boff = lr * 256 + ((ch * 16) ^ ((lr & 7) << 4));
            uint4 val = *(uint4*)((char*)Cl + boff);
            *(uint4*)(pvh + grow + ch * 8) = val;
        }
    }
    if (t < 256) {
        int btg = t >> 7, cl = t & 127;
        if (btg == 0 || btbound < i0 + 128)
            atomicAdd(&colsum[(size_t)(bt0 + btg) * DD + n0 + cl], cred[t]);
    }
}

// ---------------------------------------------------------------------------
// K3a: partial patch sums per (bt, col-quarter). grid (256,4), 768 thr.
// ---------------------------------------------------------------------------
__global__ __launch_bounds__(768) void k_patchsum(
    const unsigned short* __restrict__ pvh, const float* __restrict__ pa,
    const float* __restrict__ colsum, float* __restrict__ patch_q) {
    int bt = blockIdx.x, qd = blockIdx.y;
    int b = bt >> 3;
    size_t base = (size_t)bt * PP * DD;
    int c0 = qd * 192;
    __shared__ float2 pi[192];
    int t = threadIdx.x;
    if (t < 192) {
        int col = c0 + t;
        pi[t] = make_float2(pa[(size_t)b * DD + col],
                            1.0f / colsum[(size_t)bt * DD + col]);
    }
    __syncthreads();
    int wv = t >> 6, l = t & 63;
    for (int p = wv; p < PP; p += 12) {
        float sum = 0.f;
        if (l < 48) {
            const uint2* rv = (const uint2*)(pvh + base + (size_t)p * DD + c0);
            uint2 v = rv[l];
            int c = l * 4;
            float2 q0 = pi[c], q1 = pi[c + 1], q2 = pi[c + 2], q3 = pi[c + 3];
            sum = __expf(h2f((unsigned short)(v.x & 0xFFFFu)) * q0.x) * q0.y
                + __expf(h2f((unsigned short)(v.x >> 16)) * q1.x) * q1.y
                + __expf(h2f((unsigned short)(v.y & 0xFFFFu)) * q2.x) * q2.y
                + __expf(h2f((unsigned short)(v.y >> 16)) * q3.x) * q3.y;
        }
        #pragma unroll
        for (int o = 32; o > 0; o >>= 1) sum += __shfl_down(sum, o);
        if (l == 0) patch_q[((size_t)bt * PP + p) * 4 + qd] = sum;
    }
}

// ---------------------------------------------------------------------------
// K3b: masked sums (+ local rank-select from patch_q). grid (256 bt, 4 qd);
// 768 thr = 192 cols x 4 p-groups (49 rows each).
// ---------------------------------------------------------------------------
__global__ __launch_bounds__(768) void k_masked(
    const unsigned short* __restrict__ pvh, const unsigned short* __restrict__ visb,
    const void* __restrict__ rmask, const int* __restrict__ mode_p,
    const float* __restrict__ pa, const float* __restrict__ colsum,
    const float* __restrict__ patch_q,
    float* __restrict__ sav, float* __restrict__ vpt) {
    int bt = blockIdx.x;
    int qd = blockIdx.y;
    int b = bt >> 3;
    size_t base = (size_t)bt * PP * DD;
    __shared__ float patch[PP];
    __shared__ unsigned char spa[PP];
    __shared__ float red_s[4][192];
    __shared__ float red_v[4][192];
    int t = threadIdx.x;
    if (t < PP) {
        float4 v = *(const float4*)&patch_q[((size_t)bt * PP + t) * 4];
        patch[t] = ((v.x + v.y) + v.z) + v.w;   // fixed order: deterministic
    }
    __syncthreads();
    if (t < PP) {
        float x = patch[t];
        int c = 0;
        for (int q = 0; q < PP; ++q) c += (patch[q] <= x) ? 1 : 0;
        spa[t] = (c <= NIDX) ? 1 : 0;
    }
    int pg = t / 192;
    int c = t - pg * 192;
    int col = qd * 192 + c;
    int p0 = pg * 49, p1 = p0 + 49;
    float pav = pa[(size_t)b * DD + col];
    float inv = 1.0f / colsum[(size_t)bt * DD + col];
    __syncthreads();
    const unsigned short* pvb = pvh + base + col;
    const unsigned short* vib = visb + base + col;
    float sava = 0.f, vpa = 0.f;
    int mode = *mode_p;
    if (mode == 0) {
        const int* mb = (const int*)rmask + base + col;
        #pragma unroll 7
        for (int p = p0; p < p1; ++p) {
            float pvv = h2f(pvb[(size_t)p * DD]);
            float sa = __expf(pvv * pav) * inv;
            bool km = !(spa[p] && (mb[(size_t)p * DD] != 0));
            if (km) { sava = fmaf(sa, pvv, sava); vpa = fmaf(sa, bf2f(vib[(size_t)p * DD]), vpa); }
        }
    } else if (mode == 1) {
        const float* mb = (const float*)rmask + base + col;
        #pragma unroll 7
        for (int p = p0; p < p1; ++p) {
            float pvv = h2f(pvb[(size_t)p * DD]);
            float sa = __expf(pvv * pav) * inv;
            bool km = !(spa[p] && (mb[(size_t)p * DD] != 0.f));
            if (km) { sava = fmaf(sa, pvv, sava); vpa = fmaf(sa, bf2f(vib[(size_t)p * DD]), vpa); }
        }
    } else {
        const unsigned char* mb = (const unsigned char*)rmask + base + col;
        #pragma unroll 7
        for (int p = p0; p < p1; ++p) {
            float pvv = h2f(pvb[(size_t)p * DD]);
            float sa = __expf(pvv * pav) * inv;
            bool km = !(spa[p] && (mb[(size_t)p * DD] != 0));
            if (km) { sava = fmaf(sa, pvv, sava); vpa = fmaf(sa, bf2f(vib[(size_t)p * DD]), vpa); }
        }
    }
    red_s[pg][c] = sava;
    red_v[pg][c] = vpa;
    __syncthreads();
    if (t < 192) {
        int col2 = qd * 192 + t;
        sav[(size_t)bt * DD + col2] = red_s[0][t] + red_s[1][t] + red_s[2][t] + red_s[3][t];
        vpt[(size_t)bt * DD + col2] = red_v[0][t] + red_v[1][t] + red_v[2][t] + red_v[3][t];
    }
}

// ---------------------------------------------------------------------------
// K4: fused tail per b: temporal softmax -> vp (LDS); h = relu(vp@Wv+bv)+af
// (LDS); logits = h@Wc+bc. grid B, 768 threads.
// ---------------------------------------------------------------------------
__global__ __launch_bounds__(768) void k_tail(
    const float* __restrict__ sav, const float* __restrict__ vpt,
    const float* __restrict__ pa, const float* __restrict__ af,
    const float* __restrict__ Wv, const float* __restrict__ bv,
    const float* __restrict__ Wc, const float* __restrict__ bc,
    float* __restrict__ out) {
    int b = blockIdx.x;
    int t = threadIdx.x;
    __shared__ float vp[DD];
    __shared__ float h[DD];
    float pav = pa[(size_t)b * DD + t];
    float x[TT];
    float mx = -1e30f;
    #pragma unroll
    for (int k = 0; k < TT; ++k) {
        x[k] = sav[((size_t)b * TT + k) * DD + t] * pav;
        mx = fmaxf(mx, x[k]);
    }
    float s = 0.f;
    #pragma unroll
    for (int k = 0; k < TT; ++k) { x[k] = __expf(x[k] - mx); s += x[k]; }
    float inv = 1.0f / s;
    float acc = 0.f;
    #pragma unroll
    for (int k = 0; k < TT; ++k)
        acc += x[k] * inv * vpt[((size_t)b * TT + k) * DD + t];
    vp[t] = acc;
    __syncthreads();
    float accv = bv[t];
    #pragma unroll 8
    for (int k = 0; k < DD; ++k) accv = fmaf(vp[k], Wv[(size_t)k * DD + t], accv);
    h[t] = fmaxf(accv, 0.f) + af[(size_t)b * DD + t];
    __syncthreads();
    if (t < NCLS) {
        float accc = bc[t];
        #pragma unroll 8
        for (int k = 0; k < DD; ++k) accc = fmaf(h[k], Wc[(size_t)k * NCLS + t], accc);
        out[(size_t)b * NCLS + t] = accc;
    }
}

// ---------------------------------------------------------------------------
extern "C" void kernel_launch(void* const* d_in, const int* in_sizes, int n_in,
                              void* d_out, int out_size, void* d_ws, size_t ws_size,
                              hipStream_t stream) {
    const float* visual = (const float*)d_in[0];
    const float* audio  = (const float*)d_in[1];
    const float* causal = (const float*)d_in[2];
    const void*  rmask  = d_in[3];
    const float* Wa   = (const float*)d_in[4];
    const float* ba   = (const float*)d_in[5];
    const float* Wv   = (const float*)d_in[6];
    const float* bv   = (const float*)d_in[7];
    const float* Waa  = (const float*)d_in[8];
    const float* baa  = (const float*)d_in[9];
    const float* Wav  = (const float*)d_in[10];
    const float* bav  = (const float*)d_in[11];
    const float* Wf   = (const float*)d_in[12];
    const float* bf   = (const float*)d_in[13];
    const float* Wf2  = (const float*)d_in[14];
    const float* bf2  = (const float*)d_in[15];
    const float* Wc   = (const float*)d_in[16];
    const float* bc   = (const float*)d_in[17];
    const float* cpar = (const float*)d_in[18];
    float* out = (float*)d_out;

    const size_t NE = (size_t)BB * TT * PP * DD;   // 38,535,168
    unsigned short* Wht = (unsigned short*)d_ws;                   // D*D bf16
    float* pfreg = (float*)(Wht + (size_t)DD * DD);                // overlay region
    float* colsum = pfreg;                                         // 196608 f
    float* savw  = colsum + (size_t)BB * TT * DD;                  // 196608 f
    float* vptw  = savw + (size_t)BB * TT * DD;                    // 196608 f
    float* pf    = pfreg;                                          // alias
    float* pf2   = pfreg + (size_t)BB * 3 * MM * DD;               // 960 f (pad 1024)
    float* a2w   = pf2 + 1024;                                     // B*D
    float* paw   = a2w + (size_t)BB * DD;                          // B*D
    float* afw   = paw + (size_t)BB * DD;                          // B*D
    int*   modew = (int*)(afw + (size_t)BB * DD);                  // pad 16
    unsigned short* visb = (unsigned short*)(modew + 16);          // NE bf16
    unsigned short* pvh  = visb + NE;                              // NE f16
    float* patchq = (float*)(pvh + NE);                            // 256*196*4 f

    k_prep_all<<<1696, 768, 0, stream>>>(visual, visb, (const unsigned int*)rmask,
                                         modew, Wav, Wht, causal, Wf, Wf2, pf, pf2);
    k_audio2a<<<BB, 768, 0, stream>>>(causal, audio, pf, pf2, bf, bf2, cpar, a2w);
    k_audio2b<<<dim3(24, 2), 256, 0, stream>>>(a2w, Waa, baa, Wa, ba, paw, afw, colsum);
    k_pv_mfma<<<2352, 256, 0, stream>>>(visb, Wht, bav, paw, pvh, colsum);
    k_patchsum<<<dim3(BB * TT, 4), 768, 0, stream>>>(pvh, paw, colsum, patchq);
    k_masked<<<dim3(BB * TT, 4), 768, 0, stream>>>(pvh, visb, rmask, modew, paw,
                                                   colsum, patchq, savw, vptw);
    k_tail<<<BB, 768, 0, stream>>>(savw, vptw, paw, afw, Wv, bv, Wc, bc, out);
}